// Round 2
// baseline (45.582 us; speedup 1.0000x reference)
//
#include <hip/hip_runtime.h>

// Identity op: out = x (4096*8192 float32). Pure copy.
// Try a cached float4 grid-stride copy kernel instead of hipMemcpyAsync:
// working set (256 MiB) == L3 capacity, so cached loads may hit Infinity
// Cache across graph replays where the blit/SDMA path runs at HBM rate.

__global__ __launch_bounds__(256) void copy_f4(const float4* __restrict__ in,
                                               float4* __restrict__ out,
                                               int n4) {
    int stride = gridDim.x * blockDim.x;
    for (int i = blockIdx.x * blockDim.x + threadIdx.x; i < n4; i += stride) {
        out[i] = in[i];
    }
}

extern "C" void kernel_launch(void* const* d_in, const int* in_sizes, int n_in,
                              void* d_out, int out_size, void* d_ws, size_t ws_size,
                              hipStream_t stream) {
    const float4* x = (const float4*)d_in[0];
    float4* out = (float4*)d_out;
    int n4 = out_size / 4;  // 33554432 / 4 = 8388608, exact
    // ~2048 blocks keeps all CUs busy (8 blocks/CU) with grid-stride for the rest.
    int blocks = 2048;
    copy_f4<<<blocks, 256, 0, stream>>>(x, out, n4);
}